// Round 1
// baseline (77.306 us; speedup 1.0000x reference)
//
#include <hip/hip_runtime.h>

// Problem constants (fixed by setup_inputs)
constexpr int N = 128;     // number of RBF centers
constexpr int W = 1024;    // x extent
constexpr int L = 1024;    // y extent
constexpr float SIGMA = 32.0f;

constexpr int TX = 8;       // x rows per block
constexpr int YPT = 2;      // y pixels per thread
constexpr int THREADS = 256;
constexpr int TY = THREADS * YPT;  // 512 y cols per block

__global__ __launch_bounds__(THREADS, 1)
void rbf_field_kernel(const float* __restrict__ v,   // [2][N]
                      const int*   __restrict__ xc,  // [N]
                      const int*   __restrict__ yc,  // [N]
                      float*       __restrict__ out) // [2][W][L]
{
    // sB[n][j]: j in [0,16): c = j>>3, i = j&7 -> exp(-dx^2 k) * v[c][n]
    __shared__ __align__(16) float sB[N][2 * TX];
    __shared__ float sYc[N];

    const int tid = threadIdx.x;
    const int x0 = blockIdx.x * TX;
    const int y0 = blockIdx.y * TY + tid * YPT;

    constexpr float kInv = 1.0f / (2.0f * SIGMA * SIGMA);

    if (tid < N) sYc[tid] = (float)yc[tid];

    // Fill sB: N*2*TX = 2048 entries, 8 per thread, consecutive -> coalesced
    #pragma unroll
    for (int k = 0; k < (N * 2 * TX) / THREADS; ++k) {
        int idx = tid + k * THREADS;
        int n = idx >> 4;
        int j = idx & 15;
        int c = j >> 3;
        int i = j & 7;
        float dx = (float)(x0 + i - xc[n]);
        sB[n][j] = __expf(-dx * dx * kInv) * v[c * N + n];
    }
    __syncthreads();

    float acc[TX][2][YPT];
    #pragma unroll
    for (int i = 0; i < TX; ++i)
        #pragma unroll
        for (int c = 0; c < 2; ++c)
            #pragma unroll
            for (int q = 0; q < YPT; ++q)
                acc[i][c][q] = 0.0f;

    const float yf = (float)y0;

    #pragma unroll 4
    for (int n = 0; n < N; ++n) {
        float dy0 = yf - sYc[n];
        float dy1 = dy0 + 1.0f;
        float wy0 = __expf(-dy0 * dy0 * kInv);
        float wy1 = __expf(-dy1 * dy1 * kInv);

        // 16 contiguous LDS floats, wave-uniform address -> broadcast reads
        #pragma unroll
        for (int i = 0; i < TX; ++i) {
            float b0 = sB[n][i];        // channel 0
            float b1 = sB[n][TX + i];   // channel 1
            acc[i][0][0] += b0 * wy0;
            acc[i][0][1] += b0 * wy1;
            acc[i][1][0] += b1 * wy0;
            acc[i][1][1] += b1 * wy1;
        }
    }

    // Store: out[c][x][y], float2 per (c,x), coalesced across threads in y
    #pragma unroll
    for (int c = 0; c < 2; ++c) {
        #pragma unroll
        for (int i = 0; i < TX; ++i) {
            float2 o;
            o.x = acc[i][c][0];
            o.y = acc[i][c][1];
            *(float2*)&out[(size_t)c * W * L + (size_t)(x0 + i) * L + y0] = o;
        }
    }
}

extern "C" void kernel_launch(void* const* d_in, const int* in_sizes, int n_in,
                              void* d_out, int out_size, void* d_ws, size_t ws_size,
                              hipStream_t stream) {
    const float* v  = (const float*)d_in[0];  // init_vectors [2][128] fp32
    const int*   xc = (const int*)d_in[1];    // x_coord [128] int32
    const int*   yc = (const int*)d_in[2];    // y_coord [128] int32
    float* out = (float*)d_out;               // [1][2][1024][1024] fp32

    dim3 grid(W / TX, L / TY);   // (128, 2) = 256 blocks
    rbf_field_kernel<<<grid, THREADS, 0, stream>>>(v, xc, yc, out);
}